// Round 11
// baseline (234.263 us; speedup 1.0000x reference)
//
#include <hip/hip_runtime.h>
#include <hip/hip_fp16.h>
#include <math.h>

// ---------------------------------------------------------------------------
// FocalLoss: geodetic->ECEF->ENU error -> distance -> focal-weighted RMS.
// 2-kernel pipeline: pass1 (dist -> fp16 ws, per-block max; zeroes ticket) ->
// pass2 (fold blockmax inline + focal + partials; LAST block folds partials
// and writes the scalar via the canonical last-block-done pattern).
//
// R11 vs R10 (pass1 compute path unchanged):
//  - dist stored as fp16 (rel err 4.9e-4, output perturbation ~1e-3 vs
//    margin 0.035; max-element round-up handled by the base>=0 clamp).
//    Halves p1 write + p2 read: -16 MB HBM.
//  - k_final fused into pass2 (threadfence + ticket atomicAdd; last block
//    reduces partials). One fewer dispatch.
// ---------------------------------------------------------------------------

#define THREADS 256
#define PART_CAP 8192
#define TICKET_OFF 0
#define BMAX_OFF 64
#define PART_OFF (64 + PART_CAP * 4)                 // doubles, 8-aligned
#define DIST_OFF (1 << 20)                           // 1 MB, 16B-aligned

// ---- 8-wide breadth-first double sincos, |x| <= ~3.15 (no Payne-Hanek) ----
// fdlibm minimax, one term trimmed: abs err ~7e-12 -> 4e-5 m at N=6.4e6.
__device__ __forceinline__ void sincos8(const double* __restrict__ x,
                                        double* __restrict__ s,
                                        double* __restrict__ c) {
    const double TWO_OVER_PI = 0.636619772367581343076;
    const double PIO2_HI = 1.57079632679489655800e+00;
    const double PIO2_LO = 6.12323399573676603587e-17;

    double kd[8], r[8], r2[8];
    int q[8];
#pragma unroll
    for (int j = 0; j < 8; ++j) {
        kd[j] = rint(x[j] * TWO_OVER_PI);
        q[j] = ((int)kd[j]) & 3;
    }
#pragma unroll
    for (int j = 0; j < 8; ++j) {
        double rr = fma(-kd[j], PIO2_HI, x[j]);
        r[j] = fma(-kd[j], PIO2_LO, rr);
        r2[j] = r[j] * r[j];
    }
    double ps[8], pc[8];
#pragma unroll
    for (int j = 0; j < 8; ++j) { ps[j] = -2.50507602534068634195e-08;
                                  pc[j] =  2.08757232129817482790e-09; }
#pragma unroll
    for (int j = 0; j < 8; ++j) { ps[j] = fma(ps[j], r2[j],  2.75573137070700676789e-06);
                                  pc[j] = fma(pc[j], r2[j], -2.75573143513906633035e-07); }
#pragma unroll
    for (int j = 0; j < 8; ++j) { ps[j] = fma(ps[j], r2[j], -1.98412698298579493134e-04);
                                  pc[j] = fma(pc[j], r2[j],  2.48015872894767294178e-05); }
#pragma unroll
    for (int j = 0; j < 8; ++j) { ps[j] = fma(ps[j], r2[j],  8.33333333332248946124e-03);
                                  pc[j] = fma(pc[j], r2[j], -1.38888888888741095749e-03); }
#pragma unroll
    for (int j = 0; j < 8; ++j) { ps[j] = fma(ps[j], r2[j], -1.66666666666666324348e-01);
                                  pc[j] = fma(pc[j], r2[j],  4.16666666666666019037e-02); }
#pragma unroll
    for (int j = 0; j < 8; ++j) {
        double sv = fma(r2[j] * r[j], ps[j], r[j]);
        double cv = fma(r2[j] * r2[j], pc[j], fma(-0.5, r2[j], 1.0));
        double sr = (q[j] & 1) ? cv : sv;
        double cr = (q[j] & 1) ? sv : cv;
        s[j] = (q[j] & 2) ? -sr : sr;
        c[j] = ((q[j] + 1) & 2) ? -cr : cr;
    }
}

// ---- 4 elements, breadth-first sincos, NO rotation (|R d| == |d|) ----
__device__ __forceinline__ void dist_group4(const float* __restrict__ lat,
                                            const float* __restrict__ lon,
                                            const float* __restrict__ hh,
                                            const float* __restrict__ px,
                                            const float* __restrict__ py,
                                            const float* __restrict__ pz,
                                            float* __restrict__ dout) {
    const float D2R = (float)0.017453292519943295;   // fp32 deg2rad, matches numpy
    double x[8], s8[8], c8[8];
#pragma unroll
    for (int j = 0; j < 4; ++j) x[j] = (double)(lat[j] * D2R);
#pragma unroll
    for (int j = 0; j < 4; ++j) x[4 + j] = (double)(lon[j] * D2R);
    sincos8(x, s8, c8);

    const double A = 6378137.0, E2 = 0.00669437999014;
#pragma unroll
    for (int j = 0; j < 4; ++j) {
        double sl = s8[j], cl = c8[j], so = s8[4 + j], co = c8[4 + j];
        double h = (double)hh[j];
        double w = fma(-E2 * sl, sl, 1.0);            // [0.9933, 1]
        double y = fma(-0.5, w, 1.5);                 // rsqrt seed
        y = y * fma(-0.5 * w, y * y, 1.5);            // 2 Newton -> ~1e-19
        y = y * fma(-0.5 * w, y * y, 1.5);
        double N = A * y, Nh = N + h;
        double X = Nh * cl * co;
        double Y = Nh * cl * so;
        double Z = fma(N, -E2, N + h) * sl;           // (N*(1-E2)+h)*sl
        double dx = (double)px[j] - X;
        double dy = (double)py[j] - Y;
        double dz = (double)pz[j] - Z;
        dout[j] = sqrtf((float)(dx * dx + dy * dy + dz * dz));
    }
}

// scalar path for the tail
__device__ __forceinline__ float dist_one(float latd, float lond, float hf,
                                          float pxx, float pyy, float pzz) {
    float lat[4] = {latd, latd, latd, latd}, lon[4] = {lond, lond, lond, lond};
    float hh[4] = {hf, hf, hf, hf};
    float px[4] = {pxx, pxx, pxx, pxx}, py[4] = {pyy, pyy, pyy, pyy}, pz[4] = {pzz, pzz, pzz, pzz};
    float d[4];
    dist_group4(lat, lon, hh, px, py, pz, d);
    return d[0];
}

#define UNPACK4(ta, tb, tc, lat, lon, hh)                         \
    float lat[4] = {ta.x, ta.w, tb.z, tc.y};                      \
    float lon[4] = {ta.y, tb.x, tb.w, tc.z};                      \
    float hh[4]  = {ta.z, tb.y, tc.x, tc.w};

// pack 4 fp32 -> 4 fp16 as one 8-byte store
__device__ __forceinline__ void store_half4(__half* p, float d0, float d1, float d2, float d3) {
    union { __half2 h2[2]; uint2 u; } pk;
    pk.h2[0] = __floats2half2_rn(d0, d1);
    pk.h2[1] = __floats2half2_rn(d2, d3);
    *(uint2*)p = pk.u;
}

__global__ __launch_bounds__(THREADS, 3)
void k_pass1(const float* __restrict__ inp, const float* __restrict__ tgt,
             __half* __restrict__ dist_arr, float* __restrict__ blockmax,
             unsigned* __restrict__ ticket, long B) {
    if (threadIdx.x == 0) *ticket = 0u;   // zero the pass2 done-counter (ws is poisoned)
    long ngroups = (B + 3) >> 2;
    long nthreads = (long)gridDim.x * blockDim.x;
    long gstride = 2 * nthreads;
    float lmax = 0.0f;
    for (long g = (long)blockIdx.x * blockDim.x + threadIdx.x; g < ngroups; g += gstride) {
        long gA = g;
        long gB = g + nthreads;                       // stride-separated partner group
        long baseA = gA << 2;
        long baseB = gB << 2;
        bool fastA = (baseA + 3 < B);
        bool fastB = (gB < ngroups) && (baseB + 3 < B);

        if (fastA && fastB) {
            // hoist ALL 12 loads before any compute (2x outstanding loads)
            const float4* tA = (const float4*)(tgt + 3 * baseA);
            const float4* pA = (const float4*)(inp + 3 * baseA);
            const float4* tB = (const float4*)(tgt + 3 * baseB);
            const float4* pB = (const float4*)(inp + 3 * baseB);
            float4 ta0 = tA[0], ta1 = tA[1], ta2 = tA[2];
            float4 pa0 = pA[0], pa1 = pA[1], pa2 = pA[2];
            float4 tb0 = tB[0], tb1 = tB[1], tb2 = tB[2];
            float4 pb0 = pB[0], pb1 = pB[1], pb2 = pB[2];

            UNPACK4(ta0, ta1, ta2, latA, lonA, hhA);
            UNPACK4(pa0, pa1, pa2, pxA, pyA, pzA);
            float dA[4];
            dist_group4(latA, lonA, hhA, pxA, pyA, pzA, dA);

            UNPACK4(tb0, tb1, tb2, latB, lonB, hhB);
            UNPACK4(pb0, pb1, pb2, pxB, pyB, pzB);
            float dB[4];
            dist_group4(latB, lonB, hhB, pxB, pyB, pzB, dB);

            if (dist_arr) {
                store_half4(dist_arr + baseA, dA[0], dA[1], dA[2], dA[3]);
                store_half4(dist_arr + baseB, dB[0], dB[1], dB[2], dB[3]);
            }
            lmax = fmaxf(lmax, fmaxf(fmaxf(dA[0], dA[1]), fmaxf(dA[2], dA[3])));
            lmax = fmaxf(lmax, fmaxf(fmaxf(dB[0], dB[1]), fmaxf(dB[2], dB[3])));
        } else {
            for (int pass = 0; pass < 2; ++pass) {
                long gg = pass ? gB : gA;
                if (gg >= ngroups) continue;
                long base = gg << 2;
                long end = base + 4 < B ? base + 4 : B;
                for (long i = base; i < end; ++i) {
                    float d = dist_one(tgt[3*i], tgt[3*i+1], tgt[3*i+2],
                                       inp[3*i], inp[3*i+1], inp[3*i+2]);
                    if (dist_arr) dist_arr[i] = __float2half_rn(d);
                    lmax = fmaxf(lmax, d);
                }
            }
        }
    }
    for (int off = 32; off > 0; off >>= 1)
        lmax = fmaxf(lmax, __shfl_down(lmax, off, 64));
    __shared__ float smax[THREADS / 64];
    if ((threadIdx.x & 63) == 0) smax[threadIdx.x >> 6] = lmax;
    __syncthreads();
    if (threadIdx.x == 0) {
        float m = smax[0];
        for (int w = 1; w < THREADS / 64; ++w) m = fmaxf(m, smax[w]);
        blockmax[blockIdx.x] = m;
    }
}

__device__ __forceinline__ double focal2(float d, float denom) {
    float g = 2.0f * __expf(-d);                  // dynamic gamma (SCALE=1, GAMMA=2)
    float b = 1.0f - sqrtf(d / denom);            // true div: max elem ratio <= 1
    b = fmaxf(b, 0.0f);                           // also guards fp16 round-up past max
    float wgt = __builtin_amdgcn_exp2f(g * __log2f(b));  // b^g; log2(0)->-inf->0 ok
    float fl = wgt * d;                           // ALPHA = 1
    return (double)fl * (double)fl;
}

__global__ void k_pass2(const __half* __restrict__ dist_arr,
                        const float* __restrict__ inp,
                        const float* __restrict__ tgt,
                        const float* __restrict__ blockmax, int nb1,
                        double* __restrict__ partials,
                        unsigned* __restrict__ ticket,
                        float* __restrict__ out, long B) {
    __shared__ float smax[THREADS / 64];
    __shared__ double sacc[THREADS / 64];
    __shared__ float sb;
    __shared__ unsigned stick;
    int tid = threadIdx.x;

    // fold blockmax inline (nb1 floats, L2-hot)
    float m = 0.0f;
    for (int i = tid; i < nb1; i += THREADS) m = fmaxf(m, blockmax[i]);
    for (int off = 32; off > 0; off >>= 1)
        m = fmaxf(m, __shfl_down(m, off, 64));
    if ((tid & 63) == 0) smax[tid >> 6] = m;
    __syncthreads();
    if (tid == 0) {
        float mm = smax[0];
        for (int w = 1; w < THREADS / 64; ++w) mm = fmaxf(mm, smax[w]);
        sb = mm;
    }
    __syncthreads();
    float denom = sb + 1e-8f;

    long ngroups = (B + 3) >> 2;
    long gstride = (long)gridDim.x * blockDim.x;
    double acc = 0.0;
    for (long g = (long)blockIdx.x * blockDim.x + tid; g < ngroups; g += gstride) {
        long base = g << 2;
        if (base + 3 < B) {
            float d0, d1, d2, d3;
            if (dist_arr) {
                union { uint2 u; __half2 h2[2]; } pk;
                pk.u = *(const uint2*)(dist_arr + base);
                float2 lo = __half22float2(pk.h2[0]);
                float2 hi = __half22float2(pk.h2[1]);
                d0 = lo.x; d1 = lo.y; d2 = hi.x; d3 = hi.y;
            } else {
                const float4* t4 = (const float4*)(tgt + 3 * base);
                float4 ta = t4[0], tb = t4[1], tc = t4[2];
                const float4* p4 = (const float4*)(inp + 3 * base);
                float4 pa = p4[0], pb = p4[1], pc = p4[2];
                UNPACK4(ta, tb, tc, lat, lon, hh);
                UNPACK4(pa, pb, pc, px, py, pz);
                float d[4];
                dist_group4(lat, lon, hh, px, py, pz, d);
                d0 = d[0]; d1 = d[1]; d2 = d[2]; d3 = d[3];
            }
            acc += focal2(d0, denom) + focal2(d1, denom)
                 + focal2(d2, denom) + focal2(d3, denom);
        } else {
            for (long i = base; i < B; ++i) {
                float d = dist_arr ? __half2float(dist_arr[i])
                                   : dist_one(tgt[3*i], tgt[3*i+1], tgt[3*i+2],
                                              inp[3*i], inp[3*i+1], inp[3*i+2]);
                acc += focal2(d, denom);
            }
        }
    }
    for (int off = 32; off > 0; off >>= 1)
        acc += __shfl_down(acc, off, 64);
    if ((tid & 63) == 0) sacc[tid >> 6] = acc;
    __syncthreads();
    if (tid == 0) {
        double s = sacc[0];
        for (int w = 1; w < THREADS / 64; ++w) s += sacc[w];
        partials[blockIdx.x] = s;
        __threadfence();                          // publish partial device-wide
        stick = atomicAdd(ticket, 1u);            // device-scope ticket
    }
    __syncthreads();

    // last block folds all partials and writes the scalar
    if (stick == gridDim.x - 1) {
        __threadfence();                          // acquire side
        double a = 0.0;
        for (int i = tid; i < (int)gridDim.x; i += THREADS) a += partials[i];
        for (int off = 32; off > 0; off >>= 1)
            a += __shfl_down(a, off, 64);
        if ((tid & 63) == 0) sacc[tid >> 6] = a;
        __syncthreads();
        if (tid == 0) {
            double s = sacc[0];
            for (int w = 1; w < THREADS / 64; ++w) s += sacc[w];
            out[0] = (float)sqrt(s / (double)B);
        }
    }
}

extern "C" void kernel_launch(void* const* d_in, const int* in_sizes, int n_in,
                              void* d_out, int out_size, void* d_ws, size_t ws_size,
                              hipStream_t stream) {
    const float* inp = (const float*)d_in[0];   // (B,3) predicted ECEF
    const float* tgt = (const float*)d_in[1];   // (B,3) geodetic lat/lon/h
    float* out = (float*)d_out;
    long B = (long)in_sizes[0] / 3;

    unsigned* ticket = (unsigned*)((char*)d_ws + TICKET_OFF);
    float* blockmax = (float*)((char*)d_ws + BMAX_OFF);
    double* partials = (double*)((char*)d_ws + PART_OFF);
    __half* dist_arr = nullptr;
    size_t need = (size_t)DIST_OFF + (size_t)B * sizeof(__half);
    if (ws_size >= need) dist_arr = (__half*)((char*)d_ws + DIST_OFF);

    long ngroups = (B + 3) >> 2;

    // pass1: 2 groups per thread -> half the blocks
    long nhalf = (ngroups + 1) >> 1;
    int nb1 = (int)((nhalf + THREADS - 1) / THREADS);
    if (nb1 > PART_CAP) nb1 = PART_CAP;
    if (nb1 < 1) nb1 = 1;

    // pass2: 1 group per thread
    int nb2 = (int)((ngroups + THREADS - 1) / THREADS);
    if (nb2 > PART_CAP) nb2 = PART_CAP;
    if (nb2 < 1) nb2 = 1;

    k_pass1<<<nb1, THREADS, 0, stream>>>(inp, tgt, dist_arr, blockmax, ticket, B);
    k_pass2<<<nb2, THREADS, 0, stream>>>(dist_arr, inp, tgt, blockmax, nb1,
                                         partials, ticket, out, B);
}

// Round 12
// 131.655 us; speedup vs baseline: 1.7794x; 1.7794x over previous
//
#include <hip/hip_runtime.h>
#include <hip/hip_fp16.h>
#include <math.h>

// ---------------------------------------------------------------------------
// FocalLoss: geodetic->ECEF->ENU error -> distance -> focal-weighted RMS.
// 3-kernel pipeline: pass1 (dist -> fp16 ws, per-block max) ->
// pass2 (fold blockmax inline + focal + per-block partial) -> final.
//
// R12 = R10 structure + fp16 dist array (the one good R11 idea).
// R11 post-mortem: fused last-block-done final cost 122us — device-scope
// threadfence + same-address ticket atomic from 3907 blocks serializes
// across non-coherent per-XCD L2s. Kernel boundaries ARE the cheap
// device-wide barrier on MI355X; fences/atomics are not. Reverted.
// ---------------------------------------------------------------------------

#define THREADS 256
#define PART_CAP 8192
#define BMAX_OFF 64
#define PART_OFF (64 + PART_CAP * 4)                 // doubles, 8-aligned
#define DIST_OFF (1 << 20)                           // 1 MB, 16B-aligned

// ---- 8-wide breadth-first double sincos, |x| <= ~3.15 (no Payne-Hanek) ----
// fdlibm minimax, one term trimmed: abs err ~7e-12 -> 4e-5 m at N=6.4e6.
__device__ __forceinline__ void sincos8(const double* __restrict__ x,
                                        double* __restrict__ s,
                                        double* __restrict__ c) {
    const double TWO_OVER_PI = 0.636619772367581343076;
    const double PIO2_HI = 1.57079632679489655800e+00;
    const double PIO2_LO = 6.12323399573676603587e-17;

    double kd[8], r[8], r2[8];
    int q[8];
#pragma unroll
    for (int j = 0; j < 8; ++j) {
        kd[j] = rint(x[j] * TWO_OVER_PI);
        q[j] = ((int)kd[j]) & 3;
    }
#pragma unroll
    for (int j = 0; j < 8; ++j) {
        double rr = fma(-kd[j], PIO2_HI, x[j]);
        r[j] = fma(-kd[j], PIO2_LO, rr);
        r2[j] = r[j] * r[j];
    }
    double ps[8], pc[8];
#pragma unroll
    for (int j = 0; j < 8; ++j) { ps[j] = -2.50507602534068634195e-08;
                                  pc[j] =  2.08757232129817482790e-09; }
#pragma unroll
    for (int j = 0; j < 8; ++j) { ps[j] = fma(ps[j], r2[j],  2.75573137070700676789e-06);
                                  pc[j] = fma(pc[j], r2[j], -2.75573143513906633035e-07); }
#pragma unroll
    for (int j = 0; j < 8; ++j) { ps[j] = fma(ps[j], r2[j], -1.98412698298579493134e-04);
                                  pc[j] = fma(pc[j], r2[j],  2.48015872894767294178e-05); }
#pragma unroll
    for (int j = 0; j < 8; ++j) { ps[j] = fma(ps[j], r2[j],  8.33333333332248946124e-03);
                                  pc[j] = fma(pc[j], r2[j], -1.38888888888741095749e-03); }
#pragma unroll
    for (int j = 0; j < 8; ++j) { ps[j] = fma(ps[j], r2[j], -1.66666666666666324348e-01);
                                  pc[j] = fma(pc[j], r2[j],  4.16666666666666019037e-02); }
#pragma unroll
    for (int j = 0; j < 8; ++j) {
        double sv = fma(r2[j] * r[j], ps[j], r[j]);
        double cv = fma(r2[j] * r2[j], pc[j], fma(-0.5, r2[j], 1.0));
        double sr = (q[j] & 1) ? cv : sv;
        double cr = (q[j] & 1) ? sv : cv;
        s[j] = (q[j] & 2) ? -sr : sr;
        c[j] = ((q[j] + 1) & 2) ? -cr : cr;
    }
}

// ---- 4 elements, breadth-first sincos, NO rotation (|R d| == |d|) ----
__device__ __forceinline__ void dist_group4(const float* __restrict__ lat,
                                            const float* __restrict__ lon,
                                            const float* __restrict__ hh,
                                            const float* __restrict__ px,
                                            const float* __restrict__ py,
                                            const float* __restrict__ pz,
                                            float* __restrict__ dout) {
    const float D2R = (float)0.017453292519943295;   // fp32 deg2rad, matches numpy
    double x[8], s8[8], c8[8];
#pragma unroll
    for (int j = 0; j < 4; ++j) x[j] = (double)(lat[j] * D2R);
#pragma unroll
    for (int j = 0; j < 4; ++j) x[4 + j] = (double)(lon[j] * D2R);
    sincos8(x, s8, c8);

    const double A = 6378137.0, E2 = 0.00669437999014;
#pragma unroll
    for (int j = 0; j < 4; ++j) {
        double sl = s8[j], cl = c8[j], so = s8[4 + j], co = c8[4 + j];
        double h = (double)hh[j];
        double w = fma(-E2 * sl, sl, 1.0);            // [0.9933, 1]
        double y = fma(-0.5, w, 1.5);                 // rsqrt seed
        y = y * fma(-0.5 * w, y * y, 1.5);            // 2 Newton -> ~1e-19
        y = y * fma(-0.5 * w, y * y, 1.5);
        double N = A * y, Nh = N + h;
        double X = Nh * cl * co;
        double Y = Nh * cl * so;
        double Z = fma(N, -E2, N + h) * sl;           // (N*(1-E2)+h)*sl
        double dx = (double)px[j] - X;
        double dy = (double)py[j] - Y;
        double dz = (double)pz[j] - Z;
        dout[j] = sqrtf((float)(dx * dx + dy * dy + dz * dz));
    }
}

// scalar path for the tail
__device__ __forceinline__ float dist_one(float latd, float lond, float hf,
                                          float pxx, float pyy, float pzz) {
    float lat[4] = {latd, latd, latd, latd}, lon[4] = {lond, lond, lond, lond};
    float hh[4] = {hf, hf, hf, hf};
    float px[4] = {pxx, pxx, pxx, pxx}, py[4] = {pyy, pyy, pyy, pyy}, pz[4] = {pzz, pzz, pzz, pzz};
    float d[4];
    dist_group4(lat, lon, hh, px, py, pz, d);
    return d[0];
}

#define UNPACK4(ta, tb, tc, lat, lon, hh)                         \
    float lat[4] = {ta.x, ta.w, tb.z, tc.y};                      \
    float lon[4] = {ta.y, tb.x, tb.w, tc.z};                      \
    float hh[4]  = {ta.z, tb.y, tc.x, tc.w};

// pack 4 fp32 -> 4 fp16 as one 8-byte store
__device__ __forceinline__ void store_half4(__half* p, float d0, float d1, float d2, float d3) {
    union { __half2 h2[2]; uint2 u; } pk;
    pk.h2[0] = __floats2half2_rn(d0, d1);
    pk.h2[1] = __floats2half2_rn(d2, d3);
    *(uint2*)p = pk.u;
}

__global__ __launch_bounds__(THREADS, 3)
void k_pass1(const float* __restrict__ inp, const float* __restrict__ tgt,
             __half* __restrict__ dist_arr, float* __restrict__ blockmax, long B) {
    long ngroups = (B + 3) >> 2;
    long nthreads = (long)gridDim.x * blockDim.x;
    long gstride = 2 * nthreads;
    float lmax = 0.0f;
    for (long g = (long)blockIdx.x * blockDim.x + threadIdx.x; g < ngroups; g += gstride) {
        long gA = g;
        long gB = g + nthreads;                       // stride-separated partner group
        long baseA = gA << 2;
        long baseB = gB << 2;
        bool fastA = (baseA + 3 < B);
        bool fastB = (gB < ngroups) && (baseB + 3 < B);

        if (fastA && fastB) {
            // hoist ALL 12 loads before any compute (2x outstanding loads)
            const float4* tA = (const float4*)(tgt + 3 * baseA);
            const float4* pA = (const float4*)(inp + 3 * baseA);
            const float4* tB = (const float4*)(tgt + 3 * baseB);
            const float4* pB = (const float4*)(inp + 3 * baseB);
            float4 ta0 = tA[0], ta1 = tA[1], ta2 = tA[2];
            float4 pa0 = pA[0], pa1 = pA[1], pa2 = pA[2];
            float4 tb0 = tB[0], tb1 = tB[1], tb2 = tB[2];
            float4 pb0 = pB[0], pb1 = pB[1], pb2 = pB[2];

            UNPACK4(ta0, ta1, ta2, latA, lonA, hhA);
            UNPACK4(pa0, pa1, pa2, pxA, pyA, pzA);
            float dA[4];
            dist_group4(latA, lonA, hhA, pxA, pyA, pzA, dA);

            UNPACK4(tb0, tb1, tb2, latB, lonB, hhB);
            UNPACK4(pb0, pb1, pb2, pxB, pyB, pzB);
            float dB[4];
            dist_group4(latB, lonB, hhB, pxB, pyB, pzB, dB);

            if (dist_arr) {
                store_half4(dist_arr + baseA, dA[0], dA[1], dA[2], dA[3]);
                store_half4(dist_arr + baseB, dB[0], dB[1], dB[2], dB[3]);
            }
            lmax = fmaxf(lmax, fmaxf(fmaxf(dA[0], dA[1]), fmaxf(dA[2], dA[3])));
            lmax = fmaxf(lmax, fmaxf(fmaxf(dB[0], dB[1]), fmaxf(dB[2], dB[3])));
        } else {
            for (int pass = 0; pass < 2; ++pass) {
                long gg = pass ? gB : gA;
                if (gg >= ngroups) continue;
                long base = gg << 2;
                long end = base + 4 < B ? base + 4 : B;
                for (long i = base; i < end; ++i) {
                    float d = dist_one(tgt[3*i], tgt[3*i+1], tgt[3*i+2],
                                       inp[3*i], inp[3*i+1], inp[3*i+2]);
                    if (dist_arr) dist_arr[i] = __float2half_rn(d);
                    lmax = fmaxf(lmax, d);
                }
            }
        }
    }
    for (int off = 32; off > 0; off >>= 1)
        lmax = fmaxf(lmax, __shfl_down(lmax, off, 64));
    __shared__ float smax[THREADS / 64];
    if ((threadIdx.x & 63) == 0) smax[threadIdx.x >> 6] = lmax;
    __syncthreads();
    if (threadIdx.x == 0) {
        float m = smax[0];
        for (int w = 1; w < THREADS / 64; ++w) m = fmaxf(m, smax[w]);
        blockmax[blockIdx.x] = m;
    }
}

__device__ __forceinline__ double focal2(float d, float denom) {
    float g = 2.0f * __expf(-d);                  // dynamic gamma (SCALE=1, GAMMA=2)
    float b = 1.0f - sqrtf(d / denom);            // true div: max elem ratio <= 1
    b = fmaxf(b, 0.0f);                           // also guards fp16 round-up past max
    float wgt = __builtin_amdgcn_exp2f(g * __log2f(b));  // b^g; log2(0)->-inf->0 ok
    float fl = wgt * d;                           // ALPHA = 1
    return (double)fl * (double)fl;
}

__global__ void k_pass2(const __half* __restrict__ dist_arr,
                        const float* __restrict__ inp,
                        const float* __restrict__ tgt,
                        const float* __restrict__ blockmax, int nb1,
                        double* __restrict__ partials, long B) {
    __shared__ float smax[THREADS / 64];
    __shared__ double sacc[THREADS / 64];
    __shared__ float sb;
    int tid = threadIdx.x;

    // fold blockmax inline (nb1 floats, L2-hot)
    float m = 0.0f;
    for (int i = tid; i < nb1; i += THREADS) m = fmaxf(m, blockmax[i]);
    for (int off = 32; off > 0; off >>= 1)
        m = fmaxf(m, __shfl_down(m, off, 64));
    if ((tid & 63) == 0) smax[tid >> 6] = m;
    __syncthreads();
    if (tid == 0) {
        float mm = smax[0];
        for (int w = 1; w < THREADS / 64; ++w) mm = fmaxf(mm, smax[w]);
        sb = mm;
    }
    __syncthreads();
    float denom = sb + 1e-8f;

    long ngroups = (B + 3) >> 2;
    long gstride = (long)gridDim.x * blockDim.x;
    double acc = 0.0;
    for (long g = (long)blockIdx.x * blockDim.x + tid; g < ngroups; g += gstride) {
        long base = g << 2;
        if (base + 3 < B) {
            float d0, d1, d2, d3;
            if (dist_arr) {
                union { uint2 u; __half2 h2[2]; } pk;
                pk.u = *(const uint2*)(dist_arr + base);
                float2 lo = __half22float2(pk.h2[0]);
                float2 hi = __half22float2(pk.h2[1]);
                d0 = lo.x; d1 = lo.y; d2 = hi.x; d3 = hi.y;
            } else {
                const float4* t4 = (const float4*)(tgt + 3 * base);
                float4 ta = t4[0], tb = t4[1], tc = t4[2];
                const float4* p4 = (const float4*)(inp + 3 * base);
                float4 pa = p4[0], pb = p4[1], pc = p4[2];
                UNPACK4(ta, tb, tc, lat, lon, hh);
                UNPACK4(pa, pb, pc, px, py, pz);
                float d[4];
                dist_group4(lat, lon, hh, px, py, pz, d);
                d0 = d[0]; d1 = d[1]; d2 = d[2]; d3 = d[3];
            }
            acc += focal2(d0, denom) + focal2(d1, denom)
                 + focal2(d2, denom) + focal2(d3, denom);
        } else {
            for (long i = base; i < B; ++i) {
                float d = dist_arr ? __half2float(dist_arr[i])
                                   : dist_one(tgt[3*i], tgt[3*i+1], tgt[3*i+2],
                                              inp[3*i], inp[3*i+1], inp[3*i+2]);
                acc += focal2(d, denom);
            }
        }
    }
    for (int off = 32; off > 0; off >>= 1)
        acc += __shfl_down(acc, off, 64);
    if ((tid & 63) == 0) sacc[tid >> 6] = acc;
    __syncthreads();
    if (tid == 0) {
        double s = sacc[0];
        for (int w = 1; w < THREADS / 64; ++w) s += sacc[w];
        partials[blockIdx.x] = s;
    }
}

__global__ void k_final(const double* __restrict__ partials, int nparts,
                        float* __restrict__ out, long B) {
    double acc = 0.0;
    for (int i = threadIdx.x; i < nparts; i += blockDim.x) acc += partials[i];
    for (int off = 32; off > 0; off >>= 1)
        acc += __shfl_down(acc, off, 64);
    __shared__ double lds[THREADS / 64];
    if ((threadIdx.x & 63) == 0) lds[threadIdx.x >> 6] = acc;
    __syncthreads();
    if (threadIdx.x == 0) {
        double s = lds[0];
        for (int w = 1; w < THREADS / 64; ++w) s += lds[w];
        out[0] = (float)sqrt(s / (double)B);
    }
}

extern "C" void kernel_launch(void* const* d_in, const int* in_sizes, int n_in,
                              void* d_out, int out_size, void* d_ws, size_t ws_size,
                              hipStream_t stream) {
    const float* inp = (const float*)d_in[0];   // (B,3) predicted ECEF
    const float* tgt = (const float*)d_in[1];   // (B,3) geodetic lat/lon/h
    float* out = (float*)d_out;
    long B = (long)in_sizes[0] / 3;

    float* blockmax = (float*)((char*)d_ws + BMAX_OFF);
    double* partials = (double*)((char*)d_ws + PART_OFF);
    __half* dist_arr = nullptr;
    size_t need = (size_t)DIST_OFF + (size_t)B * sizeof(__half);
    if (ws_size >= need) dist_arr = (__half*)((char*)d_ws + DIST_OFF);

    long ngroups = (B + 3) >> 2;

    // pass1: 2 groups per thread -> half the blocks
    long nhalf = (ngroups + 1) >> 1;
    int nb1 = (int)((nhalf + THREADS - 1) / THREADS);
    if (nb1 > PART_CAP) nb1 = PART_CAP;
    if (nb1 < 1) nb1 = 1;

    // pass2: 1 group per thread
    int nb2 = (int)((ngroups + THREADS - 1) / THREADS);
    if (nb2 > PART_CAP) nb2 = PART_CAP;
    if (nb2 < 1) nb2 = 1;

    k_pass1<<<nb1, THREADS, 0, stream>>>(inp, tgt, dist_arr, blockmax, B);
    k_pass2<<<nb2, THREADS, 0, stream>>>(dist_arr, inp, tgt, blockmax, nb1, partials, B);
    k_final<<<1, THREADS, 0, stream>>>(partials, nb2, out, B);
}